// Round 6
// baseline (312.269 us; speedup 1.0000x reference)
//
#include <hip/hip_runtime.h>
#include <hip/hip_bf16.h>
#include <stdint.h>

typedef __attribute__((ext_vector_type(8))) short short8;   // 8 bf16 = 4 VGPRs
typedef __attribute__((ext_vector_type(4))) float f32x4;    // MFMA C/D frag

typedef __attribute__((address_space(3))) uint8_t lds_u8;
typedef __attribute__((address_space(1))) uint8_t glb_u8;

__device__ __forceinline__ void load_lds_16(const void* g, void* l) {
    __builtin_amdgcn_global_load_lds((glb_u8*)g, (lds_u8*)l, 16, 0, 0);
}

__device__ __forceinline__ unsigned short f2b(float f) {
    __hip_bfloat16 h = __float2bfloat16(f);
    return __builtin_bit_cast(unsigned short, h);
}
__device__ __forceinline__ ushort2 f2b2(float a, float b) {
    __hip_bfloat162 h = __float22bfloat162_rn(float2{a, b});
    ushort2 r;
    __builtin_memcpy(&r, &h, sizeof(r));
    return r;
}
__device__ __forceinline__ float b2f(unsigned short u) {
    unsigned int x = ((unsigned int)u) << 16;
    return __builtin_bit_cast(float, x);
}

constexpr int Bz = 32, Ss = 577, Dd = 768, Hh = 12;
constexpr int Mm = Bz * Ss;          // 18464
constexpr int QKV_N = 3 * Dd;        // 2304
constexpr float SCALE_L2E = 0.125f * 1.4426950408889634f;

// ---------------- cast x -> bf16 ----------------
__global__ void cast_f32_bf16(const float* __restrict__ src,
                              unsigned short* __restrict__ dst, int n4) {
    int i = blockIdx.x * blockDim.x + threadIdx.x;
    if (i >= n4) return;
    float4 v = ((const float4*)src)[i];
    ushort4 o;
    o.x = f2b(v.x); o.y = f2b(v.y); o.z = f2b(v.z); o.w = f2b(v.w);
    ((ushort4*)dst)[i] = o;
}

// ---------------- transpose + cast: src fp32 [R][C] -> dst bf16 [C][R] ----------------
__global__ void transpose_cast(const float* __restrict__ src,
                               unsigned short* __restrict__ dst, int R, int C) {
    __shared__ unsigned short tile[32][33];
    int c0 = blockIdx.x * 32, r0 = blockIdx.y * 32;
    int tx = threadIdx.x, ty = threadIdx.y;  // (32,8)
#pragma unroll
    for (int i = 0; i < 4; ++i)
        tile[ty + i * 8][tx] = f2b(src[(size_t)(r0 + ty + i * 8) * C + c0 + tx]);
    __syncthreads();
#pragma unroll
    for (int i = 0; i < 4; ++i) {
        int rr = ty + i * 8;
        dst[(size_t)(c0 + rr) * R + r0 + tx] = tile[tx][rr];
    }
}

// ========= 256x256 TN GEMM, BK=32, TRIPLE-buffered counted-vmcnt (T1+T2+T4+T5) =========
// C[M][N_] = A[M][768] * Bt[N_][768]^T + bias.  8 waves (2M x 4N), 24 K-tiles,
// 96 KiB dynamic LDS (3 bufs x 32KB: A 16KB + B 16KB each).
// r2 (8-phase, 0.5-tile vmcnt depth) and r5 (1-barrier, vmcnt(0) drain) both sat
// at ~6.5k cyc/K-tile = LDS floor + MFMA floor SERIALIZED. This version applies
// T4 properly: stage tile T+2 during tile T; end-of-tile vmcnt(4) drains only
// T+1 (in flight a full tile, ~free) while T+2's loads ride across the barrier.
// Never drains to 0 in the main loop.
//
// LDS layout (conflict-free for 64B-wide BK=32 rows): two tile-rows packed per
// 128B LDS row.  Stored slot CH for (tile row pr, k-chunk c) is
//   R = pr>>1,  CH = ((pr&1)*4 + c) ^ (R & 7)
// Stage side: gload_lds dest is linear (base + lane*16); the per-lane GLOBAL
// source applies the inverse permutation (rule #21): lane (w,l) covers LDS row
// lr = s*64+w*8+(l>>3), slot l&7  ->  CH_un = (l&7)^(lr&7), tile row =
// lr*2 + (CH_un>>2), k-chunk = CH_un&3.  Read side: slot index
// S = ((lc&1)*4+quad) ^ ((lc>>1)&7) is m/n-independent -> frag addr = one base
// + m*1024 compile-time immediates (kills the 19% VALUBusy address overhead).
// Per wave per tile: 4 gload_lds, 12 ds_read_b128 (no B re-read), 32 MFMA.
// NOTE (r3 lesson): acc = 128 regs/wave -> 2 waves/SIMD hard ceiling; keep
// __launch_bounds__(512,2), never demand more (forces spill, 7x slowdown).
template <int N_, bool OUT_BF16>
__global__ __launch_bounds__(512, 2)
void gemm256(const unsigned short* __restrict__ A,
             const unsigned short* __restrict__ Bt,
             const float* __restrict__ bias,
             void* __restrict__ Cout) {
    constexpr int K = 768;
    constexpr int KB = 24;               // K / 32
    constexpr int NX = N_ / 256;
    constexpr int NY = (Mm + 255) / 256; // 73
    constexpr int NWG = NX * NY;
    constexpr int QC = NWG >> 3, RC = NWG & 7;
    extern __shared__ __align__(16) uint8_t smem[];   // 98304 B = 3 x 32768

    const int tid = threadIdx.x;
    const int wave = tid >> 6, lane = tid & 63;
    const int quad = lane >> 4, lc = lane & 15;
    const int wm = wave >> 2, wn = wave & 3;

    // XCD-aware bijective remap (m204)
    const int orig = blockIdx.y * NX + blockIdx.x;
    const int xcd = orig & 7, lid = orig >> 3;
    const int wgid = (xcd < RC ? xcd * (QC + 1) : RC * (QC + 1) + (xcd - RC) * QC) + lid;
    const int tm = (wgid / NX) * 256;
    const int tn = (wgid % NX) * 256;

    // ---- staging source pointers (per-lane, inverse-swizzled)
    const int lrw = wave * 8 + (lane >> 3);   // LDS row within segment (s=0)
    const unsigned short* apS[2];
    const unsigned short* bpS[2];
#pragma unroll
    for (int s = 0; s < 2; ++s) {
        const int lr = s * 64 + lrw;
        const int chun = (lane & 7) ^ (lr & 7);
        const int trow = lr * 2 + (chun >> 2);
        int ar = tm + trow; if (ar >= Mm) ar = Mm - 1;   // M-tail clamp (store guarded)
        apS[s] = A + (size_t)ar * K + (chun & 3) * 8;
        const int br = tn + trow;
        bpS[s] = Bt + (size_t)br * K + (chun & 3) * 8;
    }

    auto stage = [&](int kb, int buf) {
        uint8_t* d = smem + buf * 32768 + wave * 1024;
        const int ko = kb * 32;
        load_lds_16(apS[0] + ko, d);
        load_lds_16(apS[1] + ko, d + 8192);
        load_lds_16(bpS[0] + ko, d + 16384);
        load_lds_16(bpS[1] + ko, d + 24576);
    };

    // ---- fragment read bases (slot S independent of m/n -> immediate offsets)
    const int slotS = (((lane & 1) << 2) + quad) ^ ((lc >> 1) & 7);
    // careful: (lc&1) == (lane&1) since lc = lane&15
    const int aoff = (wm * 64 + (lc >> 1)) * 128 + slotS * 16;
    const int boff = 16384 + (wn * 32 + (lc >> 1)) * 128 + slotS * 16;

    short8 af[8], bf[4];
    auto readfr = [&](int buf) {
        const uint8_t* p = smem + buf * 32768;
#pragma unroll
        for (int m = 0; m < 8; ++m) af[m] = *(const short8*)(p + aoff + m * 1024);
#pragma unroll
        for (int n = 0; n < 4; ++n) bf[n] = *(const short8*)(p + boff + n * 1024);
    };

    f32x4 acc[8][4] = {};
    auto mfmas = [&]() {
        __builtin_amdgcn_s_setprio(1);
#pragma unroll
        for (int m = 0; m < 8; ++m)
#pragma unroll
            for (int n = 0; n < 4; ++n)
                acc[m][n] = __builtin_amdgcn_mfma_f32_16x16x32_bf16(af[m], bf[n], acc[m][n], 0, 0, 0);
        __builtin_amdgcn_s_setprio(0);
    };

    // ---- prologue: tiles 0,1 staged; drain tile 0 only (tile 1 rides across)
    stage(0, 0);
    stage(1, 1);
    asm volatile("s_waitcnt vmcnt(4)" ::: "memory");
    __builtin_amdgcn_s_barrier();

    // ---- main loop T = 0..20 (7 x 3, compile-time buffer indices)
#pragma unroll 1
    for (int t3 = 0; t3 < 7; ++t3) {
        const int T = t3 * 3;
#pragma unroll
        for (int u = 0; u < 3; ++u) {
            const int rb = u;                 // (T+u) % 3 == u  (T multiple of 3)
            const int sb = (u + 2) % 3;
            stage(T + u + 2, sb);
            readfr(rb);
            mfmas();
            asm volatile("s_waitcnt vmcnt(4)" ::: "memory");   // drain T+u+1, keep T+u+2
            __builtin_amdgcn_s_barrier();
        }
    }
    // ---- T=21: stage 23 (buf 2), drain 22
    stage(23, 2);
    readfr(0);
    mfmas();
    asm volatile("s_waitcnt vmcnt(4)" ::: "memory");
    __builtin_amdgcn_s_barrier();
    // ---- T=22: no stage; drain 23 (issued a full tile ago)
    readfr(1);
    mfmas();
    asm volatile("s_waitcnt vmcnt(0)" ::: "memory");
    __builtin_amdgcn_s_barrier();
    // ---- T=23
    readfr(2);
    mfmas();
    __builtin_amdgcn_s_barrier();   // protect epilogue smem reuse

    // ---- epilogue: wave-private LDS transpose (reuses buf0 region), vector stores
    float bv[4];
#pragma unroll
    for (int j = 0; j < 4; ++j) bv[j] = bias[tn + wn * 64 + j * 16 + lc];

    float* ep = (float*)smem + wave * (16 * 68);   // 4352 B/wave
    const int erow = lane >> 2, ec = (lane & 3) * 16;
#pragma unroll
    for (int ia = 0; ia < 8; ++ia) {
#pragma unroll
        for (int j = 0; j < 4; ++j)
#pragma unroll
            for (int r = 0; r < 4; ++r)
                ep[(quad * 4 + r) * 68 + j * 16 + lc] = acc[ia][j][r] + bv[j];
        __threadfence_block();   // wave-local LDS ordering
        int grow = tm + wm * 128 + ia * 16 + erow;
        if (grow < Mm) {
            float4 c0 = *(float4*)&ep[erow * 68 + ec + 0];
            float4 c1 = *(float4*)&ep[erow * 68 + ec + 4];
            float4 c2 = *(float4*)&ep[erow * 68 + ec + 8];
            float4 c3 = *(float4*)&ep[erow * 68 + ec + 12];
            int gcol = tn + wn * 64 + ec;
            if constexpr (OUT_BF16) {
                unsigned short o[16];
                *(ushort2*)&o[0]  = f2b2(c0.x, c0.y);
                *(ushort2*)&o[2]  = f2b2(c0.z, c0.w);
                *(ushort2*)&o[4]  = f2b2(c1.x, c1.y);
                *(ushort2*)&o[6]  = f2b2(c1.z, c1.w);
                *(ushort2*)&o[8]  = f2b2(c2.x, c2.y);
                *(ushort2*)&o[10] = f2b2(c2.z, c2.w);
                *(ushort2*)&o[12] = f2b2(c3.x, c3.y);
                *(ushort2*)&o[14] = f2b2(c3.z, c3.w);
                unsigned short* op = (unsigned short*)Cout + (size_t)grow * N_ + gcol;
                *(short8*)(op + 0) = *(short8*)&o[0];
                *(short8*)(op + 8) = *(short8*)&o[8];
            } else {
                float* op = (float*)Cout + (size_t)grow * N_ + gcol;
                *(float4*)(op + 0)  = c0;
                *(float4*)(op + 4)  = c1;
                *(float4*)(op + 8)  = c2;
                *(float4*)(op + 12) = c3;
            }
        }
        __threadfence_block();
    }
}

// ---------------- flash attention (S^T, no-max softmax, MFMA l-sum) ----------------
// 9 full tiles cover keys 0..575; key 576 handled by a register VALU tail.
__device__ __forceinline__ void attn_tile(
    const unsigned short* __restrict__ Ktile,  // LDS [64 key][64 dh], chunk-swizzled
    const unsigned short* __restrict__ Vtb,    // LDS V^T [80 rows][80 keys]; row64=ones
    unsigned short* __restrict__ Pqw,          // per-wave [16 q][72 keys]
    const short8& qf0, const short8& qf1,
    int quad, int lc,
    f32x4 (&oacc)[4], f32x4& lacc) {

    const int sw = lc & 7;
    f32x4 sfr[4];
    __builtin_amdgcn_s_setprio(1);
#pragma unroll
    for (int f = 0; f < 4; ++f) {
        const unsigned short* kr = Ktile + (f * 16 + lc) * 64;
        short8 k0 = *(const short8*)(kr + (quad ^ sw) * 8);
        short8 k1 = *(const short8*)(kr + ((quad ^ 4) ^ sw) * 8);
        f32x4 z = {};
        z = __builtin_amdgcn_mfma_f32_16x16x32_bf16(k0, qf0, z, 0, 0, 0);
        z = __builtin_amdgcn_mfma_f32_16x16x32_bf16(k1, qf1, z, 0, 0, 0);
        sfr[f] = z;
    }
    __builtin_amdgcn_s_setprio(0);

#pragma unroll
    for (int f = 0; f < 4; ++f) {
        float p[4];
#pragma unroll
        for (int r = 0; r < 4; ++r)
            p[r] = __builtin_amdgcn_exp2f(sfr[f][r] * SCALE_L2E);
        ushort2 lo = f2b2(p[0], p[1]), hi = f2b2(p[2], p[3]);
        ushort4 pk = {lo.x, lo.y, hi.x, hi.y};
        *(ushort4*)&Pqw[lc * 72 + f * 16 + quad * 4] = pk;
    }

    __threadfence_block();

    short8 pf0 = *(const short8*)&Pqw[lc * 72 + quad * 8];
    short8 pf1 = *(const short8*)&Pqw[lc * 72 + 32 + quad * 8];
    __builtin_amdgcn_s_setprio(1);
#pragma unroll
    for (int g = 0; g < 4; ++g) {
        short8 vf0 = *(const short8*)&Vtb[(g * 16 + lc) * 80 + quad * 8];
        short8 vf1 = *(const short8*)&Vtb[(g * 16 + lc) * 80 + 32 + quad * 8];
        oacc[g] = __builtin_amdgcn_mfma_f32_16x16x32_bf16(vf0, pf0, oacc[g], 0, 0, 0);
        oacc[g] = __builtin_amdgcn_mfma_f32_16x16x32_bf16(vf1, pf1, oacc[g], 0, 0, 0);
    }
    short8 vo0 = *(const short8*)&Vtb[(64 + lc) * 80 + quad * 8];
    short8 vo1 = *(const short8*)&Vtb[(64 + lc) * 80 + 32 + quad * 8];
    lacc = __builtin_amdgcn_mfma_f32_16x16x32_bf16(vo0, pf0, lacc, 0, 0, 0);
    lacc = __builtin_amdgcn_mfma_f32_16x16x32_bf16(vo1, pf1, lacc, 0, 0, 0);
    __builtin_amdgcn_s_setprio(0);
}

__global__ __launch_bounds__(512)
void attn_kernel(const unsigned short* __restrict__ qkv,   // [Mm][2304] bf16
                 unsigned short* __restrict__ outb) {      // [Mm][768] bf16
    __shared__ unsigned short Kt[2][64 * 64];
    __shared__ unsigned short Vt[2][80 * 80];
    __shared__ unsigned short Pq[8][16 * 72];

    const int tid = threadIdx.x;
    const int wave = tid >> 6, lane = tid & 63;
    const int quad = lane >> 4, lc = lane & 15;

    const int orig = (blockIdx.z * gridDim.y + blockIdx.y) * gridDim.x + blockIdx.x;
    const int wgid = (orig & 7) * 240 + (orig >> 3);
    const int qt = wgid % 5;
    const int h  = (wgid / 5) % Hh;
    const int b  = wgid / (5 * Hh);

    const unsigned short* qkvK = qkv + (size_t)b * Ss * QKV_N + h * 64 + 768;
    const unsigned short* qkvV = qkvK + 768;

    const int krow = lane >> 3;
    const int gch = (lane & 7) ^ krow;

    const int qbase = qt * 128 + wave * 16;
    int qrow = qbase + lc; if (qrow > Ss - 1) qrow = Ss - 1;
    const unsigned short* qp = qkv + (size_t)(b * Ss + qrow) * QKV_N + h * 64;
    short8 qf0 = *(const short8*)(qp + quad * 8);
    short8 qf1 = *(const short8*)(qp + 32 + quad * 8);

    unsigned short* Pqw = Pq[wave];

    auto stage_K = [&](int tile, int buf) {
        int key = tile * 64 + wave * 8 + krow;       // tile<=8 -> key<=575, in range
        const unsigned short* gp = qkvK + (size_t)key * QKV_N + gch * 8;
        load_lds_16(gp, (void*)&Kt[buf][wave * 512]);
    };
    auto load_V = [&](int tile) -> short8 {
        int key = tile * 64 + lane;                  // tile<=8 -> key<=575
        return *(const short8*)(qkvV + (size_t)key * QKV_N + wave * 8);
    };
    auto write_V = [&](short8 v, int buf) {
#pragma unroll
        for (int j = 0; j < 8; ++j)
            Vt[buf][(wave * 8 + j) * 80 + lane] = (unsigned short)v[j];
    };

    if (tid < 80) {
        Vt[0][64 * 80 + tid] = 0x3F80;   // bf16 1.0
        Vt[1][64 * 80 + tid] = 0x3F80;
    }

    f32x4 oacc[4] = {};
    f32x4 lacc = {};

    stage_K(0, 0);
    write_V(load_V(0), 0);
    __syncthreads();

    for (int kb = 0; kb < 8; ++kb) {
        const int buf = kb & 1;
        stage_K(kb + 1, buf ^ 1);
        short8 vreg = load_V(kb + 1);
        attn_tile(Kt[buf], Vt[buf], Pqw, qf0, qf1, quad, lc, oacc, lacc);
        write_V(vreg, buf ^ 1);
        __syncthreads();
    }
    attn_tile(Kt[0], Vt[0], Pqw, qf0, qf1, quad, lc, oacc, lacc);   // tile 8 (buf 0)

    // ---- key 576 in registers: p = exp2(q.k576 * C); l += p; O^T[:,q] += p*v576
    float ptail;
    {
        const unsigned short* k576 = qkvK + (size_t)576 * QKV_N;
        short8 kk0 = *(const short8*)(k576 + quad * 8);
        short8 kk1 = *(const short8*)(k576 + 32 + quad * 8);
        float part = 0.f;
#pragma unroll
        for (int j = 0; j < 8; ++j)
            part += b2f((unsigned short)qf0[j]) * b2f((unsigned short)kk0[j])
                  + b2f((unsigned short)qf1[j]) * b2f((unsigned short)kk1[j]);
        part += __shfl_xor(part, 16, 64);
        part += __shfl_xor(part, 32, 64);           // full dot for q-row lc, all quads
        ptail = __builtin_amdgcn_exp2f(part * SCALE_L2E);
        const unsigned short* v576 = qkvV + (size_t)576 * QKV_N;
#pragma unroll
        for (int g = 0; g < 4; ++g) {
            ushort4 vv = *(const ushort4*)(v576 + g * 16 + quad * 4);
            oacc[g][0] += ptail * b2f(vv.x);
            oacc[g][1] += ptail * b2f(vv.y);
            oacc[g][2] += ptail * b2f(vv.z);
            oacc[g][3] += ptail * b2f(vv.w);
        }
    }

    // ---- epilogue: l broadcast (+tail), O^T -> LDS transpose -> coalesced store
    float lq = __shfl(lacc[0], lc, 64) + ptail;   // l[q] from lanes 0..15 + tail p
    float inv = 1.f / lq;
#pragma unroll
    for (int g = 0; g < 4; ++g) {
        ushort2 lo = f2b2(oacc[g][0] * inv, oacc[g][1] * inv);
        ushort2 hi = f2b2(oacc[g][2] * inv, oacc[g][3] * inv);
        ushort4 ob = {lo.x, lo.y, hi.x, hi.y};
        *(ushort4*)&Pqw[lc * 72 + g * 16 + quad * 4] = ob;
    }
    __threadfence_block();
#pragma unroll
    for (int p = 0; p < 2; ++p) {
        int lr = p * 8 + (lane >> 3), ch = lane & 7;
        int q = qbase + lr;
        if (q <= Ss - 1) {
            short8 vv = *(const short8*)&Pqw[lr * 72 + ch * 8];
            *(short8*)(outb + (size_t)(b * Ss + q) * Dd + h * 64 + ch * 8) = vv;
        }
    }
}

extern "C" void kernel_launch(void* const* d_in, const int* in_sizes, int n_in,
                              void* d_out, int out_size, void* d_ws, size_t ws_size,
                              hipStream_t stream) {
    const float* x     = (const float*)d_in[0];
    const float* w_qkv = (const float*)d_in[1];
    const float* b_qkv = (const float*)d_in[2];
    const float* w_fc  = (const float*)d_in[3];
    const float* b_fc  = (const float*)d_in[4];

    uint8_t* ws = (uint8_t*)d_ws;
    unsigned short* xb    = (unsigned short*)(ws + 0);           //  28,360,704 B
    unsigned short* wqkvT = (unsigned short*)(ws + 28360704);    //   3,538,944 B
    unsigned short* wfcT  = (unsigned short*)(ws + 31899648);    //   1,179,648 B
    unsigned short* qkv   = (unsigned short*)(ws + 33079296);    //  85,082,112 B
    unsigned short* attn  = (unsigned short*)(ws + 118161408);   //  28,360,704 B

    // 96 KiB dynamic LDS opt-in (one-time; host-side, capture-safe)
    static bool lds_init = false;
    if (!lds_init) {
        hipFuncSetAttribute((const void*)gemm256<QKV_N, true>,
                            hipFuncAttributeMaxDynamicSharedMemorySize, 98304);
        hipFuncSetAttribute((const void*)gemm256<Dd, false>,
                            hipFuncAttributeMaxDynamicSharedMemorySize, 98304);
        lds_init = true;
    }

    int n4 = (Mm * Dd) / 4;
    cast_f32_bf16<<<(n4 + 255) / 256, 256, 0, stream>>>(x, xb, n4);
    transpose_cast<<<dim3(QKV_N / 32, Dd / 32), dim3(32, 8), 0, stream>>>(w_qkv, wqkvT, Dd, QKV_N);
    transpose_cast<<<dim3(Dd / 32, Dd / 32), dim3(32, 8), 0, stream>>>(w_fc, wfcT, Dd, Dd);

    gemm256<QKV_N, true><<<dim3(QKV_N / 256, (Mm + 255) / 256), 512, 98304, stream>>>(xb, wqkvT, b_qkv, qkv);

    attn_kernel<<<dim3(5, Hh, Bz), 512, 0, stream>>>(qkv, attn);

    gemm256<Dd, false><<<dim3(Dd / 256, (Mm + 255) / 256), 512, 98304, stream>>>(attn, wfcT, b_fc, d_out);
}

// Round 7
// 307.428 us; speedup vs baseline: 1.0157x; 1.0157x over previous
//
#include <hip/hip_runtime.h>
#include <hip/hip_bf16.h>
#include <stdint.h>

typedef __attribute__((ext_vector_type(8))) short short8;   // 8 bf16 = 4 VGPRs
typedef __attribute__((ext_vector_type(4))) float f32x4;    // MFMA C/D frag

typedef __attribute__((address_space(3))) uint8_t lds_u8;
typedef __attribute__((address_space(1))) uint8_t glb_u8;

__device__ __forceinline__ void load_lds_16(const void* g, void* l) {
    __builtin_amdgcn_global_load_lds((glb_u8*)g, (lds_u8*)l, 16, 0, 0);
}

__device__ __forceinline__ unsigned short f2b(float f) {
    __hip_bfloat16 h = __float2bfloat16(f);
    return __builtin_bit_cast(unsigned short, h);
}
__device__ __forceinline__ ushort2 f2b2(float a, float b) {
    __hip_bfloat162 h = __float22bfloat162_rn(float2{a, b});
    ushort2 r;
    __builtin_memcpy(&r, &h, sizeof(r));
    return r;
}
__device__ __forceinline__ float b2f(unsigned short u) {
    unsigned int x = ((unsigned int)u) << 16;
    return __builtin_bit_cast(float, x);
}

constexpr int Bz = 32, Ss = 577, Dd = 768, Hh = 12;
constexpr int Mm = Bz * Ss;          // 18464
constexpr int QKV_N = 3 * Dd;        // 2304
constexpr float SCALE_L2E = 0.125f * 1.4426950408889634f;

// ---------------- fused prep: cast x->bf16 + both weight transposes ----------------
// One launch instead of three (launch-gap diagnostic + saves 2 gaps).
__global__ void prep_fused(const float* __restrict__ x, unsigned short* __restrict__ xb,
                           const float* __restrict__ w_qkv, unsigned short* __restrict__ wqkvT,
                           const float* __restrict__ w_fc, unsigned short* __restrict__ wfcT) {
    constexpr int N4 = Mm * Dd / 4;          // 3,545,088 (multiple of 256)
    constexpr int NC = N4 / 256;             // 13848 cast blocks
    constexpr int NT1 = (QKV_N / 32) * (Dd / 32);   // 72*24 = 1728
    __shared__ unsigned short tile[32][33];

    const int bid = blockIdx.x;
    const int tid = threadIdx.x;
    if (bid < NC) {
        int i = bid * 256 + tid;
        float4 v = ((const float4*)x)[i];
        ushort4 o;
        o.x = f2b(v.x); o.y = f2b(v.y); o.z = f2b(v.z); o.w = f2b(v.w);
        ((ushort4*)xb)[i] = o;
        return;
    }
    const float* src; unsigned short* dst; int R, C, bx, by;
    if (bid < NC + NT1) {
        int b2 = bid - NC;
        src = w_qkv; dst = wqkvT; R = Dd; C = QKV_N;
        bx = b2 % (QKV_N / 32); by = b2 / (QKV_N / 32);
    } else {
        int b2 = bid - NC - NT1;
        src = w_fc; dst = wfcT; R = Dd; C = Dd;
        bx = b2 % (Dd / 32); by = b2 / (Dd / 32);
    }
    int c0 = bx * 32, r0 = by * 32;
    int tx = tid & 31, ty = tid >> 5;   // (32,8)
#pragma unroll
    for (int i = 0; i < 4; ++i)
        tile[ty + i * 8][tx] = f2b(src[(size_t)(r0 + ty + i * 8) * C + c0 + tx]);
    __syncthreads();
#pragma unroll
    for (int i = 0; i < 4; ++i) {
        int rr = ty + i * 8;
        dst[(size_t)(c0 + rr) * R + r0 + tx] = tile[tx][rr];
    }
}

// ========= 256x256 TN GEMM, BK=32, triple-buffered counted-vmcnt (r6, 82us) =========
// Structural operating point: per K-tile = MFMA floor (1242cy) + LDS floors
// (~1400cy) serialized under 1-block/CU lockstep; schedule variants (8-phase,
// 1-barrier, counted-3buf) all land 82-87us. Do not re-litigate without >2
// blocks/CU (impossible: 128-reg accumulator; r3 spill disaster).
template <int N_, bool OUT_BF16>
__global__ __launch_bounds__(512, 2)
void gemm256(const unsigned short* __restrict__ A,
             const unsigned short* __restrict__ Bt,
             const float* __restrict__ bias,
             void* __restrict__ Cout) {
    constexpr int K = 768;
    constexpr int NX = N_ / 256;
    constexpr int NY = (Mm + 255) / 256; // 73
    constexpr int NWG = NX * NY;
    constexpr int QC = NWG >> 3, RC = NWG & 7;
    extern __shared__ __align__(16) uint8_t smem[];   // 98304 B = 3 x 32768

    const int tid = threadIdx.x;
    const int wave = tid >> 6, lane = tid & 63;
    const int quad = lane >> 4, lc = lane & 15;
    const int wm = wave >> 2, wn = wave & 3;

    const int orig = blockIdx.y * NX + blockIdx.x;
    const int xcd = orig & 7, lid = orig >> 3;
    const int wgid = (xcd < RC ? xcd * (QC + 1) : RC * (QC + 1) + (xcd - RC) * QC) + lid;
    const int tm = (wgid / NX) * 256;
    const int tn = (wgid % NX) * 256;

    const int lrw = wave * 8 + (lane >> 3);
    const unsigned short* apS[2];
    const unsigned short* bpS[2];
#pragma unroll
    for (int s = 0; s < 2; ++s) {
        const int lr = s * 64 + lrw;
        const int chun = (lane & 7) ^ (lr & 7);
        const int trow = lr * 2 + (chun >> 2);
        int ar = tm + trow; if (ar >= Mm) ar = Mm - 1;
        apS[s] = A + (size_t)ar * K + (chun & 3) * 8;
        const int br = tn + trow;
        bpS[s] = Bt + (size_t)br * K + (chun & 3) * 8;
    }

    auto stage = [&](int kb, int buf) {
        uint8_t* d = smem + buf * 32768 + wave * 1024;
        const int ko = kb * 32;
        load_lds_16(apS[0] + ko, d);
        load_lds_16(apS[1] + ko, d + 8192);
        load_lds_16(bpS[0] + ko, d + 16384);
        load_lds_16(bpS[1] + ko, d + 24576);
    };

    const int slotS = (((lane & 1) << 2) + quad) ^ ((lc >> 1) & 7);
    const int aoff = (wm * 64 + (lc >> 1)) * 128 + slotS * 16;
    const int boff = 16384 + (wn * 32 + (lc >> 1)) * 128 + slotS * 16;

    short8 af[8], bf[4];
    auto readfr = [&](int buf) {
        const uint8_t* p = smem + buf * 32768;
#pragma unroll
        for (int m = 0; m < 8; ++m) af[m] = *(const short8*)(p + aoff + m * 1024);
#pragma unroll
        for (int n = 0; n < 4; ++n) bf[n] = *(const short8*)(p + boff + n * 1024);
    };

    f32x4 acc[8][4] = {};
    auto mfmas = [&]() {
        __builtin_amdgcn_s_setprio(1);
#pragma unroll
        for (int m = 0; m < 8; ++m)
#pragma unroll
            for (int n = 0; n < 4; ++n)
                acc[m][n] = __builtin_amdgcn_mfma_f32_16x16x32_bf16(af[m], bf[n], acc[m][n], 0, 0, 0);
        __builtin_amdgcn_s_setprio(0);
    };

    stage(0, 0);
    stage(1, 1);
    asm volatile("s_waitcnt vmcnt(4)" ::: "memory");
    __builtin_amdgcn_s_barrier();

#pragma unroll 1
    for (int t3 = 0; t3 < 7; ++t3) {
        const int T = t3 * 3;
#pragma unroll
        for (int u = 0; u < 3; ++u) {
            const int sb = (u + 2) % 3;
            stage(T + u + 2, sb);
            readfr(u);
            mfmas();
            asm volatile("s_waitcnt vmcnt(4)" ::: "memory");
            __builtin_amdgcn_s_barrier();
        }
    }
    stage(23, 2);
    readfr(0);
    mfmas();
    asm volatile("s_waitcnt vmcnt(4)" ::: "memory");
    __builtin_amdgcn_s_barrier();
    readfr(1);
    mfmas();
    asm volatile("s_waitcnt vmcnt(0)" ::: "memory");
    __builtin_amdgcn_s_barrier();
    readfr(2);
    mfmas();
    __builtin_amdgcn_s_barrier();

    float bv[4];
#pragma unroll
    for (int j = 0; j < 4; ++j) bv[j] = bias[tn + wn * 64 + j * 16 + lc];

    float* ep = (float*)smem + wave * (16 * 68);
    const int erow = lane >> 2, ec = (lane & 3) * 16;
#pragma unroll
    for (int ia = 0; ia < 8; ++ia) {
#pragma unroll
        for (int j = 0; j < 4; ++j)
#pragma unroll
            for (int r = 0; r < 4; ++r)
                ep[(quad * 4 + r) * 68 + j * 16 + lc] = acc[ia][j][r] + bv[j];
        __threadfence_block();
        int grow = tm + wm * 128 + ia * 16 + erow;
        if (grow < Mm) {
            float4 c0 = *(float4*)&ep[erow * 68 + ec + 0];
            float4 c1 = *(float4*)&ep[erow * 68 + ec + 4];
            float4 c2 = *(float4*)&ep[erow * 68 + ec + 8];
            float4 c3 = *(float4*)&ep[erow * 68 + ec + 12];
            int gcol = tn + wn * 64 + ec;
            if constexpr (OUT_BF16) {
                unsigned short o[16];
                *(ushort2*)&o[0]  = f2b2(c0.x, c0.y);
                *(ushort2*)&o[2]  = f2b2(c0.z, c0.w);
                *(ushort2*)&o[4]  = f2b2(c1.x, c1.y);
                *(ushort2*)&o[6]  = f2b2(c1.z, c1.w);
                *(ushort2*)&o[8]  = f2b2(c2.x, c2.y);
                *(ushort2*)&o[10] = f2b2(c2.z, c2.w);
                *(ushort2*)&o[12] = f2b2(c3.x, c3.y);
                *(ushort2*)&o[14] = f2b2(c3.z, c3.w);
                unsigned short* op = (unsigned short*)Cout + (size_t)grow * N_ + gcol;
                *(short8*)(op + 0) = *(short8*)&o[0];
                *(short8*)(op + 8) = *(short8*)&o[8];
            } else {
                float* op = (float*)Cout + (size_t)grow * N_ + gcol;
                *(float4*)(op + 0)  = c0;
                *(float4*)(op + 4)  = c1;
                *(float4*)(op + 8)  = c2;
                *(float4*)(op + 12) = c3;
            }
        }
        __threadfence_block();
    }
}

// ---------------- flash attention: 4 waves x 32q, K/V frags shared across halves ----------------
// Per wave per tile: K 8 + Pw 8 + Pr 4 + V 8 + ones 2 = 30 LDS instr for 32 q
// (was 24 per 16 q) -> ~40% less DS-pipe traffic, the attn bottleneck.
// Numerics identical to r6: bf16 P, MFMA ones-row l-sum, key-576 VALU tail.
__global__ __launch_bounds__(256)
void attn_kernel(const unsigned short* __restrict__ qkv,   // [Mm][2304] bf16
                 unsigned short* __restrict__ outb) {      // [Mm][768] bf16
    __shared__ unsigned short Kt[2][64 * 64];   // 16 KB, chunk-swizzled
    __shared__ unsigned short Vt[2][80 * 72];   // V^T stride 72; row 64 = ones, 65-79 slack
    __shared__ unsigned short Pq[4][32 * 72];   // per-wave P^T rows=q(32), cols=key

    const int tid = threadIdx.x;
    const int wave = tid >> 6, lane = tid & 63;
    const int quad = lane >> 4, lc = lane & 15;

    const int orig = (blockIdx.z * gridDim.y + blockIdx.y) * gridDim.x + blockIdx.x;
    const int wgid = (orig & 7) * 240 + (orig >> 3);   // 1920 blocks, 240/XCD
    const int qt = wgid % 5;
    const int h  = (wgid / 5) % Hh;
    const int b  = wgid / (5 * Hh);

    const unsigned short* qkvK = qkv + (size_t)b * Ss * QKV_N + h * 64 + 768;
    const unsigned short* qkvV = qkvK + 768;

    const int krow = lane >> 3;
    const int gch = (lane & 7) ^ krow;

    const int qbase = qt * 128 + wave * 32;
    short8 qf[2][2];
#pragma unroll
    for (int hf = 0; hf < 2; ++hf) {
        int qrow = qbase + hf * 16 + lc; if (qrow > Ss - 1) qrow = Ss - 1;
        const unsigned short* qp = qkv + (size_t)(b * Ss + qrow) * QKV_N + h * 64;
        qf[hf][0] = *(const short8*)(qp + quad * 8);
        qf[hf][1] = *(const short8*)(qp + 32 + quad * 8);
    }

    unsigned short* Pqw = Pq[wave];

    auto stage_K = [&](int tile, int buf) {
#pragma unroll
        for (int s = 0; s < 2; ++s) {
            int key = tile * 64 + s * 32 + wave * 8 + krow;   // tile<=8 -> key<=575
            load_lds_16(qkvK + (size_t)key * QKV_N + gch * 8,
                        (void*)&Kt[buf][(s * 32 + wave * 8) * 64]);
        }
    };
    auto load_V = [&](int tile, short8 v[2]) {
        int key = tile * 64 + lane;
#pragma unroll
        for (int s = 0; s < 2; ++s)
            v[s] = *(const short8*)(qkvV + (size_t)key * QKV_N + (s * 32 + wave * 8));
    };
    auto write_V = [&](short8 v[2], int buf) {
#pragma unroll
        for (int s = 0; s < 2; ++s)
#pragma unroll
            for (int j = 0; j < 8; ++j)
                Vt[buf][(s * 32 + wave * 8 + j) * 72 + lane] = (unsigned short)v[s][j];
    };

    if (tid < 72) {
        Vt[0][64 * 72 + tid] = 0x3F80;   // bf16 1.0 (ones row for MFMA l-sum)
        Vt[1][64 * 72 + tid] = 0x3F80;
    }

    f32x4 oacc[2][4] = {};
    f32x4 lacc[2] = {};

    auto tile_compute = [&](int buf) {
        const int sw = lc & 7;
        // ---- K frags once per tile (8 b128), reused by both q-halves
        short8 k0[4], k1[4];
        #pragma unroll
        for (int f = 0; f < 4; ++f) {
            const unsigned short* kr = &Kt[buf][(f * 16 + lc) * 64];
            k0[f] = *(const short8*)(kr + (quad ^ sw) * 8);
            k1[f] = *(const short8*)(kr + ((quad ^ 4) ^ sw) * 8);
        }
        // ---- S^T, exp2, pack per half
        #pragma unroll
        for (int hf = 0; hf < 2; ++hf) {
            f32x4 sfr[4];
            __builtin_amdgcn_s_setprio(1);
            #pragma unroll
            for (int f = 0; f < 4; ++f) {
                f32x4 z = {};
                z = __builtin_amdgcn_mfma_f32_16x16x32_bf16(k0[f], qf[hf][0], z, 0, 0, 0);
                z = __builtin_amdgcn_mfma_f32_16x16x32_bf16(k1[f], qf[hf][1], z, 0, 0, 0);
                sfr[f] = z;
            }
            __builtin_amdgcn_s_setprio(0);
            #pragma unroll
            for (int f = 0; f < 4; ++f) {
                float p0 = __builtin_amdgcn_exp2f(sfr[f][0] * SCALE_L2E);
                float p1 = __builtin_amdgcn_exp2f(sfr[f][1] * SCALE_L2E);
                float p2 = __builtin_amdgcn_exp2f(sfr[f][2] * SCALE_L2E);
                float p3 = __builtin_amdgcn_exp2f(sfr[f][3] * SCALE_L2E);
                ushort2 lo = f2b2(p0, p1), hi = f2b2(p2, p3);
                ushort4 pk = {lo.x, lo.y, hi.x, hi.y};
                *(ushort4*)&Pqw[(hf * 16 + lc) * 72 + f * 16 + quad * 4] = pk;
            }
        }
        __threadfence_block();   // wave-local P visibility (per-wave buffer)
        // ---- P frags both halves, V frags once, PV + l-sum
        short8 pf[2][2];
        #pragma unroll
        for (int hf = 0; hf < 2; ++hf) {
            pf[hf][0] = *(const short8*)&Pqw[(hf * 16 + lc) * 72 + quad * 8];
            pf[hf][1] = *(const short8*)&Pqw[(hf * 16 + lc) * 72 + 32 + quad * 8];
        }
        __builtin_amdgcn_s_setprio(1);
        #pragma unroll
        for (int g = 0; g < 4; ++g) {
            short8 vf0 = *(const short8*)&Vt[buf][(g * 16 + lc) * 72 + quad * 8];
            short8 vf1 = *(const short8*)&Vt[buf][(g * 16 + lc) * 72 + 32 + quad * 8];
            oacc[0][g] = __builtin_amdgcn_mfma_f32_16x16x32_bf16(vf0, pf[0][0], oacc[0][g], 0, 0, 0);
            oacc[0][g] = __builtin_amdgcn_mfma_f32_16x16x32_bf16(vf1, pf[0][1], oacc[0][g], 0, 0, 0);
            oacc[1][g] = __builtin_amdgcn_mfma_f32_16x16x32_bf16(vf0, pf[1][0], oacc[1][g], 0, 0, 0);
            oacc[1][g] = __builtin_amdgcn_mfma_f32_16x16x32_bf16(vf1, pf[1][1], oacc[1][g], 0, 0, 0);
        }
        short8 vo0 = *(const short8*)&Vt[buf][(64 + lc) * 72 + quad * 8];
        short8 vo1 = *(const short8*)&Vt[buf][(64 + lc) * 72 + 32 + quad * 8];
        #pragma unroll
        for (int hf = 0; hf < 2; ++hf) {
            lacc[hf] = __builtin_amdgcn_mfma_f32_16x16x32_bf16(vo0, pf[hf][0], lacc[hf], 0, 0, 0);
            lacc[hf] = __builtin_amdgcn_mfma_f32_16x16x32_bf16(vo1, pf[hf][1], lacc[hf], 0, 0, 0);
        }
        __builtin_amdgcn_s_setprio(0);
    };

    short8 vreg[2];
    stage_K(0, 0);
    load_V(0, vreg);
    write_V(vreg, 0);
    __syncthreads();

    for (int kb = 0; kb < 8; ++kb) {
        const int buf = kb & 1;
        stage_K(kb + 1, buf ^ 1);
        load_V(kb + 1, vreg);
        tile_compute(buf);
        write_V(vreg, buf ^ 1);
        __syncthreads();
    }
    tile_compute(0);   // tile 8 (buf 0)

    // ---- key 576 tail per half (register VALU)
    float ptl[2];
    {
        const unsigned short* k576 = qkvK + (size_t)576 * QKV_N;
        short8 kk0 = *(const short8*)(k576 + quad * 8);
        short8 kk1 = *(const short8*)(k576 + 32 + quad * 8);
        const unsigned short* v576 = qkvV + (size_t)576 * QKV_N;
#pragma unroll
        for (int hf = 0; hf < 2; ++hf) {
            float part = 0.f;
#pragma unroll
            for (int j = 0; j < 8; ++j)
                part += b2f((unsigned short)qf[hf][0][j]) * b2f((unsigned short)kk0[j])
                      + b2f((unsigned short)qf[hf][1][j]) * b2f((unsigned short)kk1[j]);
            part += __shfl_xor(part, 16, 64);
            part += __shfl_xor(part, 32, 64);
            ptl[hf] = __builtin_amdgcn_exp2f(part * SCALE_L2E);
#pragma unroll
            for (int g = 0; g < 4; ++g) {
                ushort4 vv = *(const ushort4*)(v576 + g * 16 + quad * 4);
                oacc[hf][g][0] += ptl[hf] * b2f(vv.x);
                oacc[hf][g][1] += ptl[hf] * b2f(vv.y);
                oacc[hf][g][2] += ptl[hf] * b2f(vv.z);
                oacc[hf][g][3] += ptl[hf] * b2f(vv.w);
            }
        }
    }

    // ---- epilogue: per-half l broadcast, normalize, LDS transpose, store
#pragma unroll
    for (int hf = 0; hf < 2; ++hf) {
        float lq = __shfl(lacc[hf][0], lc, 64) + ptl[hf];
        float inv = 1.f / lq;
#pragma unroll
        for (int g = 0; g < 4; ++g) {
            ushort2 lo = f2b2(oacc[hf][g][0] * inv, oacc[hf][g][1] * inv);
            ushort2 hi = f2b2(oacc[hf][g][2] * inv, oacc[hf][g][3] * inv);
            ushort4 ob = {lo.x, lo.y, hi.x, hi.y};
            *(ushort4*)&Pqw[(hf * 16 + lc) * 72 + g * 16 + quad * 4] = ob;
        }
    }
    __threadfence_block();
#pragma unroll
    for (int p = 0; p < 4; ++p) {
        int lr = p * 8 + (lane >> 3), ch = lane & 7;
        int q = qbase + lr;
        if (q <= Ss - 1) {
            short8 vv = *(const short8*)&Pqw[lr * 72 + ch * 8];
            *(short8*)(outb + (size_t)(b * Ss + q) * Dd + h * 64 + ch * 8) = vv;
        }
    }
}

extern "C" void kernel_launch(void* const* d_in, const int* in_sizes, int n_in,
                              void* d_out, int out_size, void* d_ws, size_t ws_size,
                              hipStream_t stream) {
    const float* x     = (const float*)d_in[0];
    const float* w_qkv = (const float*)d_in[1];
    const float* b_qkv = (const float*)d_in[2];
    const float* w_fc  = (const float*)d_in[3];
    const float* b_fc  = (const float*)d_in[4];

    uint8_t* ws = (uint8_t*)d_ws;
    unsigned short* xb    = (unsigned short*)(ws + 0);           //  28,360,704 B
    unsigned short* wqkvT = (unsigned short*)(ws + 28360704);    //   3,538,944 B
    unsigned short* wfcT  = (unsigned short*)(ws + 31899648);    //   1,179,648 B
    unsigned short* qkv   = (unsigned short*)(ws + 33079296);    //  85,082,112 B
    unsigned short* attn  = (unsigned short*)(ws + 118161408);   //  28,360,704 B

    static bool lds_init = false;
    if (!lds_init) {
        hipFuncSetAttribute((const void*)gemm256<QKV_N, true>,
                            hipFuncAttributeMaxDynamicSharedMemorySize, 98304);
        hipFuncSetAttribute((const void*)gemm256<Dd, false>,
                            hipFuncAttributeMaxDynamicSharedMemorySize, 98304);
        lds_init = true;
    }

    constexpr int PREP_GRID = (Mm * Dd / 4) / 256 + (QKV_N / 32) * (Dd / 32) + (Dd / 32) * (Dd / 32);
    prep_fused<<<PREP_GRID, 256, 0, stream>>>(x, xb, w_qkv, wqkvT, w_fc, wfcT);

    gemm256<QKV_N, true><<<dim3(QKV_N / 256, (Mm + 255) / 256), 512, 98304, stream>>>(xb, wqkvT, b_qkv, qkv);

    attn_kernel<<<dim3(5, Hh, Bz), 256, 0, stream>>>(qkv, attn);

    gemm256<Dd, false><<<dim3(Dd / 256, (Mm + 255) / 256), 512, 98304, stream>>>(attn, wfcT, b_fc, d_out);
}